// Round 1
// baseline (143.393 us; speedup 1.0000x reference)
//
#include <hip/hip_runtime.h>

#define NNODES 8192
#define NEDGES 16384
#define DD 128
#define RR 64
#define BB 16

// ws layout (floats):
//   fw     : [0, 1048576)            64*128*128  combined relation weights
//   counts : [1048576, 1572864)      8192*64     per-(tgt,rel) edge counts
//   swT    : [1572864, 1589248)      128*128     self_weight transposed
#define FW_OFF     0
#define CNT_OFF    (RR*DD*DD)
#define SWT_OFF    (RR*DD*DD + NNODES*RR)
#define PREP_TOTAL (RR*DD*DD + NNODES*RR + DD*DD)

__global__ __launch_bounds__(256) void prep_kernel(
    const float* __restrict__ weight,      // [16,128,128]
    const float* __restrict__ w_comp,      // [64,16]
    const float* __restrict__ self_weight, // [128,128]
    float* __restrict__ ws) {
  int idx = blockIdx.x * 256 + threadIdx.x;
  if (idx < RR * DD * DD) {
    int r = idx >> 14;            // idx / (128*128)
    int ij = idx & (DD * DD - 1);
    float acc = 0.f;
#pragma unroll
    for (int b = 0; b < BB; ++b)
      acc += w_comp[r * BB + b] * weight[b * DD * DD + ij];
    ws[FW_OFF + idx] = acc;
  } else if (idx < RR * DD * DD + NNODES * RR) {
    ws[CNT_OFF + (idx - RR * DD * DD)] = 0.f;
  } else if (idx < PREP_TOTAL) {
    int t = idx - (RR * DD * DD + NNODES * RR);
    int i = t >> 7, j = t & (DD - 1);
    ws[SWT_OFF + i * DD + j] = self_weight[j * DD + i];
  }
}

__global__ __launch_bounds__(256) void count_kernel(
    const int* __restrict__ deprel,
    const int* __restrict__ edge_index,
    float* __restrict__ counts) {
  int e = blockIdx.x * 256 + threadIdx.x;
  if (e < NEDGES) {
    int rel = deprel[e];
    int tgt = edge_index[NEDGES + e];
    atomicAdd(&counts[tgt * RR + rel], 1.0f);
  }
}

// out[n][j] = bias[j] + sum_i inp[n][i] * swT[i][j]   (32 nodes per block)
__global__ __launch_bounds__(256) void self_kernel(
    const float* __restrict__ inp,
    const float* __restrict__ swT,
    const float* __restrict__ bias,
    float* __restrict__ out) {
  __shared__ __align__(16) float xs[DD * 32];  // xs[i][m]
  const int tid = threadIdx.x;
  const int n0 = blockIdx.x * 32;
  {
    int m = tid & 31, ih = tid >> 5;  // lane-per-node, 8 i-chunks
    const float4* srcp = reinterpret_cast<const float4*>(inp + (n0 + m) * DD + ih * 16);
#pragma unroll
    for (int k = 0; k < 4; ++k) {
      float4 v = srcp[k];
      int i = ih * 16 + k * 4;
      xs[(i + 0) * 32 + m] = v.x;
      xs[(i + 1) * 32 + m] = v.y;
      xs[(i + 2) * 32 + m] = v.z;
      xs[(i + 3) * 32 + m] = v.w;
    }
  }
  __syncthreads();
  const int jq = tid & 31, mg = tid >> 5;
  const int j0 = jq * 4, m0 = mg * 4;
  float acc[4][4] = {};
#pragma unroll 4
  for (int i = 0; i < DD; ++i) {
    float4 x4 = *reinterpret_cast<const float4*>(&xs[i * 32 + m0]);
    float4 w4 = *reinterpret_cast<const float4*>(swT + i * DD + j0);
    acc[0][0] += x4.x * w4.x; acc[0][1] += x4.x * w4.y; acc[0][2] += x4.x * w4.z; acc[0][3] += x4.x * w4.w;
    acc[1][0] += x4.y * w4.x; acc[1][1] += x4.y * w4.y; acc[1][2] += x4.y * w4.z; acc[1][3] += x4.y * w4.w;
    acc[2][0] += x4.z * w4.x; acc[2][1] += x4.z * w4.y; acc[2][2] += x4.z * w4.z; acc[2][3] += x4.z * w4.w;
    acc[3][0] += x4.w * w4.x; acc[3][1] += x4.w * w4.y; acc[3][2] += x4.w * w4.z; acc[3][3] += x4.w * w4.w;
  }
  float4 b4 = *reinterpret_cast<const float4*>(bias + j0);
#pragma unroll
  for (int mi = 0; mi < 4; ++mi) {
    float4 o;
    o.x = acc[mi][0] + b4.x; o.y = acc[mi][1] + b4.y;
    o.z = acc[mi][2] + b4.z; o.w = acc[mi][3] + b4.w;
    *reinterpret_cast<float4*>(out + (n0 + m0 + mi) * DD + j0) = o;
  }
}

// Relation-binned edge matvec + scatter. Grid = 64 rels * 8 chunks.
__global__ __launch_bounds__(256) void edge_kernel(
    const float* __restrict__ inp,
    const int* __restrict__ deprel,
    const int* __restrict__ edge_index,
    const float* __restrict__ fw,
    const float* __restrict__ counts,
    float* __restrict__ out) {
  __shared__ int q[NEDGES / 8];  // worst case: whole chunk is one relation
  __shared__ int qn;
  __shared__ __align__(16) float xs[DD * 32];  // xs[i][m], pre-scaled by 1/count
  __shared__ int tq[32];
  __shared__ int sq[32];
  __shared__ float cq[32];
  const int tid = threadIdx.x;
  const int r = blockIdx.x >> 3;
  const int chunk = blockIdx.x & 7;
  const int e_lo = chunk * (NEDGES / 8);
  const int e_hi = e_lo + (NEDGES / 8);
  if (tid == 0) qn = 0;
  __syncthreads();
  for (int e = e_lo + tid; e < e_hi; e += 256)
    if (deprel[e] == r) { int p = atomicAdd(&qn, 1); q[p] = e; }
  __syncthreads();
  const int n = qn;
  const float* fwr = fw + r * DD * DD;

  for (int t0 = 0; t0 < n; t0 += 32) {
    if (tid < 32) {
      int mm = t0 + tid;
      if (mm < n) {
        int e = q[mm];
        sq[tid] = edge_index[e];
        int t = edge_index[NEDGES + e];
        tq[tid] = t;
        cq[tid] = 1.0f / counts[t * RR + r];
      } else {
        sq[tid] = 0; tq[tid] = 0; cq[tid] = 0.f;
      }
    }
    __syncthreads();
    {
      int m = tid & 31, ih = tid >> 5;
      int s = sq[m];
      float scale = cq[m];
      const float4* srcp = reinterpret_cast<const float4*>(inp + s * DD + ih * 16);
#pragma unroll
      for (int k = 0; k < 4; ++k) {
        float4 v = srcp[k];
        int i = ih * 16 + k * 4;
        xs[(i + 0) * 32 + m] = v.x * scale;
        xs[(i + 1) * 32 + m] = v.y * scale;
        xs[(i + 2) * 32 + m] = v.z * scale;
        xs[(i + 3) * 32 + m] = v.w * scale;
      }
    }
    __syncthreads();
    const int jq = tid & 31, mg = tid >> 5;
    const int j0 = jq * 4, m0 = mg * 4;
    float acc[4][4] = {};
#pragma unroll 4
    for (int i = 0; i < DD; ++i) {
      float4 x4 = *reinterpret_cast<const float4*>(&xs[i * 32 + m0]);
      float4 w4 = *reinterpret_cast<const float4*>(fwr + i * DD + j0);
      acc[0][0] += x4.x * w4.x; acc[0][1] += x4.x * w4.y; acc[0][2] += x4.x * w4.z; acc[0][3] += x4.x * w4.w;
      acc[1][0] += x4.y * w4.x; acc[1][1] += x4.y * w4.y; acc[1][2] += x4.y * w4.z; acc[1][3] += x4.y * w4.w;
      acc[2][0] += x4.z * w4.x; acc[2][1] += x4.z * w4.y; acc[2][2] += x4.z * w4.z; acc[2][3] += x4.z * w4.w;
      acc[3][0] += x4.w * w4.x; acc[3][1] += x4.w * w4.y; acc[3][2] += x4.w * w4.z; acc[3][3] += x4.w * w4.w;
    }
#pragma unroll
    for (int mi = 0; mi < 4; ++mi) {
      int m = m0 + mi;
      if (t0 + m < n) {
        float* orow = out + tq[m] * DD + j0;
        atomicAdd(&orow[0], acc[mi][0]);
        atomicAdd(&orow[1], acc[mi][1]);
        atomicAdd(&orow[2], acc[mi][2]);
        atomicAdd(&orow[3], acc[mi][3]);
      }
    }
    __syncthreads();  // protect xs/headers before next tile
  }
}

extern "C" void kernel_launch(void* const* d_in, const int* in_sizes, int n_in,
                              void* d_out, int out_size, void* d_ws, size_t ws_size,
                              hipStream_t stream) {
  const float* inp        = (const float*)d_in[0];
  const int*   deprel     = (const int*)d_in[1];
  const int*   edge_index = (const int*)d_in[2];
  const float* weight     = (const float*)d_in[3];
  const float* w_comp     = (const float*)d_in[4];
  const float* self_w     = (const float*)d_in[5];
  const float* bias       = (const float*)d_in[6];
  float* out = (float*)d_out;
  float* ws  = (float*)d_ws;

  float* fw     = ws + FW_OFF;
  float* counts = ws + CNT_OFF;
  float* swT    = ws + SWT_OFF;

  prep_kernel<<<(PREP_TOTAL + 255) / 256, 256, 0, stream>>>(weight, w_comp, self_w, ws);
  count_kernel<<<(NEDGES + 255) / 256, 256, 0, stream>>>(deprel, edge_index, counts);
  self_kernel<<<NNODES / 32, 256, 0, stream>>>(inp, swT, bias, out);
  edge_kernel<<<RR * 8, 256, 0, stream>>>(inp, deprel, edge_index, fw, counts, out);
}